// Round 1
// baseline (52032.434 us; speedup 1.0000x reference)
//
#include <hip/hip_runtime.h>
#include <hip/hip_bf16.h>

// ---------------- problem constants ----------------
#define UNITS   2000
#define FDIM    256
#define TSTEPS  1024
#define BATCH   64
#define KPAD    2304      // 2000 (h) + 256 (u) + 48 zero pad = 32*72
#define NPAD    2048      // 64 col-blocks * 32 cols (cols >= 2000 are zero pad)
#define KITERS  72        // KPAD / 32
#define NBLOCKS 128       // 64 col-blocks * 2 batch halves
#define NCB     64

typedef __attribute__((ext_vector_type(8))) short short8;   // 8 bf16 (A/B frag)
typedef __attribute__((ext_vector_type(4))) float f32x4;    // C/D frag

static __device__ __forceinline__ ushort f2bf(float x) {
  union { float f; unsigned u; } v; v.f = x;
  unsigned r = v.u + 0x7fff + ((v.u >> 16) & 1);   // round-to-nearest-even
  return (ushort)(r >> 16);
}
static __device__ __forceinline__ float bf2f(ushort h) {
  union { float f; unsigned u; } v; v.u = ((unsigned)h) << 16;
  return v.f;
}

// ---------------- W prep: transpose + bf16 hi/lo split ----------------
// Wt[n][k] = (k<2000 ? W_res[k][n] : k<2256 ? W_in[k-2000][n] : 0), zero-padded.
__global__ void prep_w(const float* __restrict__ W_in, const float* __restrict__ W_res,
                       ushort* __restrict__ Wth, ushort* __restrict__ Wtl) {
  __shared__ float tile[32][33];
  const int tk = blockIdx.x;             // 0..71
  const int tn = blockIdx.y;             // 0..63
  const int tx = threadIdx.x;            // 0..31
  const int ty = threadIdx.y;            // 0..7
  const int n = tn * 32 + tx;
  #pragma unroll
  for (int i = 0; i < 32; i += 8) {
    const int k = tk * 32 + ty + i;
    float v = 0.f;
    if (n < UNITS) {
      if (k < UNITS)            v = W_res[(size_t)k * UNITS + n];
      else if (k < UNITS+FDIM)  v = W_in[(size_t)(k - UNITS) * UNITS + n];
    }
    tile[ty + i][tx] = v;
  }
  __syncthreads();
  #pragma unroll
  for (int i = 0; i < 32; i += 8) {
    const int row = tn * 32 + ty + i;    // output n
    const int kk  = tk * 32 + tx;        // output k (contiguous across lanes)
    const float v = tile[tx][ty + i];
    const ushort hi = f2bf(v);
    const ushort lo = f2bf(v - bf2f(hi));
    Wth[(size_t)row * KPAD + kk] = hi;
    Wtl[(size_t)row * KPAD + kk] = lo;
  }
}

// ---------------- A-buffer init: h=0, u_0 loaded, pads zero, barrier zero ----
__global__ void init_abuf(const float* __restrict__ inp,
                          ushort* a0h, ushort* a0l, ushort* a1h, ushort* a1l,
                          unsigned* bar) {
  const int i = blockIdx.x * 256 + threadIdx.x;
  if (i == 0) { bar[0] = 0u; bar[1] = 0u; }
  if (i >= BATCH * KPAD) return;
  const int b = i / KPAD, k = i % KPAD;
  ushort hi = 0, lo = 0;
  if (k >= UNITS && k < UNITS + FDIM) {
    const float u = inp[(size_t)b * TSTEPS * FDIM + (k - UNITS)];   // t = 0
    hi = f2bf(u); lo = f2bf(u - bf2f(hi));
  }
  a0h[i] = hi; a0l[i] = lo; a1h[i] = 0; a1l[i] = 0;
}

// ---------------- the scan ----------------
// 128 blocks x 256 thr. Block (pb,cb): batches [pb*32,+32), cols [cb*32,+32).
// Wave w: m-tile (w>>1), n-tile (w&1). bf16x3: hi*Whi + hi*Wlo + lo*Whi.
__global__ void __launch_bounds__(256)
esn_scan(const float* __restrict__ inp, const float* __restrict__ alpha,
         const ushort* __restrict__ Wth, const ushort* __restrict__ Wtl,
         ushort* __restrict__ a0h, ushort* __restrict__ a0l,
         ushort* __restrict__ a1h, ushort* __restrict__ a1l,
         float* __restrict__ out, unsigned* __restrict__ bar) {
  const int cb   = blockIdx.x & 63;
  const int pb   = blockIdx.x >> 6;
  const int w    = threadIdx.x >> 6;
  const int lane = threadIdx.x & 63;
  const int l15  = lane & 15, lk = lane >> 4;

  const int mrow = pb * 32 + (w >> 1) * 16 + l15;   // A-frag batch row
  const int ncol = cb * 32 + (w & 1) * 16 + l15;    // B-frag col
  const ushort* Bh = Wth + (size_t)ncol * KPAD + lk * 8;
  const ushort* Bl = Wtl + (size_t)ncol * KPAD + lk * 8;

  ushort* AH[2] = {a0h, a1h};
  ushort* AL[2] = {a0l, a1l};

  // epilogue mapping: D lane l, reg r -> row (l>>4)*4+r, col l&15
  const int erow0 = pb * 32 + (w >> 1) * 16 + lk * 4;
  const int ecol  = cb * 32 + (w & 1) * 16 + l15;
  const float av  = (ecol < UNITS) ? alpha[ecol] : 0.f;

  for (int t = 0; t < TSTEPS; ++t) {
    const int cur = t & 1, nxt = cur ^ 1;
    const ushort* Ah = AH[cur] + (size_t)mrow * KPAD + lk * 8;
    const ushort* Al = AL[cur] + (size_t)mrow * KPAD + lk * 8;

    f32x4 acc[4];
    #pragma unroll
    for (int j = 0; j < 4; ++j) acc[j] = (f32x4){0.f, 0.f, 0.f, 0.f};

    for (int ko = 0; ko < KITERS; ko += 4) {
      #pragma unroll
      for (int j = 0; j < 4; ++j) {
        const int ki = ko + j;
        const short8 ah = *(const short8*)(Ah + ki * 32);
        const short8 al = *(const short8*)(Al + ki * 32);
        const short8 bh = *(const short8*)(Bh + ki * 32);
        const short8 bl = *(const short8*)(Bl + ki * 32);
        acc[j] = __builtin_amdgcn_mfma_f32_16x16x32_bf16(ah, bh, acc[j], 0, 0, 0);
        acc[j] = __builtin_amdgcn_mfma_f32_16x16x32_bf16(ah, bl, acc[j], 0, 0, 0);
        acc[j] = __builtin_amdgcn_mfma_f32_16x16x32_bf16(al, bh, acc[j], 0, 0, 0);
      }
    }
    const f32x4 accs = acc[0] + acc[1] + acc[2] + acc[3];

    // epilogue: h_new = (1-a)*h + a*tanh(pre); write bf16 hi/lo to next buffer
    if (ecol < UNITS) {
      #pragma unroll
      for (int r = 0; r < 4; ++r) {
        const int b = erow0 + r;
        const size_t idx = (size_t)b * KPAD + ecol;
        const float hold = bf2f(AH[cur][idx]) + bf2f(AL[cur][idx]);
        const float hn = (1.f - av) * hold + av * tanhf(accs[r]);
        const ushort hi = f2bf(hn);
        AH[nxt][idx] = hi;
        AL[nxt][idx] = f2bf(hn - bf2f(hi));
        if (t == TSTEPS - 1) out[(size_t)b * UNITS + ecol] = hn;
      }
    }

    // u_{t+1} staging: blocks (pb==1, cb<16) -> 4 batches each, 256 thr cover 4x256
    if (pb == 1 && cb < 16 && t + 1 < TSTEPS) {
      const int b  = cb * 4 + (threadIdx.x >> 6);
      const int f0 = (threadIdx.x & 63) * 4;
      const float4 uv = *(const float4*)(inp + (size_t)b * TSTEPS * FDIM
                                             + (size_t)(t + 1) * FDIM + f0);
      const size_t base = (size_t)b * KPAD + UNITS + f0;
      const ushort h0 = f2bf(uv.x), h1 = f2bf(uv.y), h2 = f2bf(uv.z), h3 = f2bf(uv.w);
      ushort4 hs = {h0, h1, h2, h3};
      ushort4 ls = {f2bf(uv.x - bf2f(h0)), f2bf(uv.y - bf2f(h1)),
                    f2bf(uv.z - bf2f(h2)), f2bf(uv.w - bf2f(h3))};
      *(ushort4*)(AH[nxt] + base) = hs;
      *(ushort4*)(AL[nxt] + base) = ls;
    }

    // ---- device-wide sense barrier (bar[0]=counter, bar[1]=generation) ----
    __syncthreads();
    if (threadIdx.x == 0) {
      __threadfence();  // flush this block's h writes past per-XCD L2
      const unsigned g = __hip_atomic_load(bar + 1, __ATOMIC_RELAXED, __HIP_MEMORY_SCOPE_AGENT);
      const unsigned arr = __hip_atomic_fetch_add(bar, 1u, __ATOMIC_ACQ_REL, __HIP_MEMORY_SCOPE_AGENT);
      if (arr == NBLOCKS - 1) {
        __hip_atomic_store(bar, 0u, __ATOMIC_RELAXED, __HIP_MEMORY_SCOPE_AGENT);
        __hip_atomic_fetch_add(bar + 1, 1u, __ATOMIC_RELEASE, __HIP_MEMORY_SCOPE_AGENT);
      } else {
        while (__hip_atomic_load(bar + 1, __ATOMIC_ACQUIRE, __HIP_MEMORY_SCOPE_AGENT) == g) {
          __builtin_amdgcn_s_sleep(1);
        }
      }
      __threadfence();  // invalidate stale L1/L2 before next step's reads
    }
    __syncthreads();
  }
}

// ---------------- launch ----------------
extern "C" void kernel_launch(void* const* d_in, const int* in_sizes, int n_in,
                              void* d_out, int out_size, void* d_ws, size_t ws_size,
                              hipStream_t stream) {
  const float* inp   = (const float*)d_in[0];   // (64,1024,256)
  const float* W_in  = (const float*)d_in[1];   // (256,2000)
  const float* W_res = (const float*)d_in[2];   // (2000,2000)
  const float* alpha = (const float*)d_in[3];   // (1,2000)
  float* out = (float*)d_out;                   // (64,2000)

  ushort* Wth = (ushort*)d_ws;
  ushort* Wtl = Wth + (size_t)NPAD * KPAD;
  ushort* a0h = Wtl + (size_t)NPAD * KPAD;
  ushort* a0l = a0h + (size_t)BATCH * KPAD;
  ushort* a1h = a0l + (size_t)BATCH * KPAD;
  ushort* a1l = a1h + (size_t)BATCH * KPAD;
  unsigned* bar = (unsigned*)(a1l + (size_t)BATCH * KPAD);   // 2 uints, 4B aligned

  hipLaunchKernelGGL(prep_w, dim3(KITERS, NCB), dim3(32, 8), 0, stream,
                     W_in, W_res, Wth, Wtl);
  hipLaunchKernelGGL(init_abuf, dim3((BATCH * KPAD + 255) / 256), dim3(256), 0, stream,
                     inp, a0h, a0l, a1h, a1l, bar);
  hipLaunchKernelGGL(esn_scan, dim3(NBLOCKS), dim3(256), 0, stream,
                     inp, alpha, Wth, Wtl, a0h, a0l, a1h, a1l, out, bar);
}

// Round 2
// 23142.003 us; speedup vs baseline: 2.2484x; 2.2484x over previous
//
#include <hip/hip_runtime.h>
#include <hip/hip_bf16.h>

// ---------------- problem constants ----------------
#define UNITS    2000
#define FDIM     256
#define TSTEPS   1024
#define BATCH    64
#define KPAD     2304                  // 2000 h + 256 u + 48 pad = 32*72
#define NPAD     2048                  // 128 col-groups * 16
#define AELEMS   (BATCH*KPAD + 1024)   // + tail slack
#define WELEMS   ((size_t)NPAD * KPAD)
#define WLSTR    2312                  // LDS row stride (ushorts): +8 pad -> 2-way bank alias only
#define REDOFF   (2*16*WLSTR)          // ushort offset of fp32 reduction scratch
#define SMEM_BYTES (REDOFF*2 + 2048)   // 147,968 + 2,048 = 150,016 B
#define NBLK     256

typedef __attribute__((ext_vector_type(8))) short short8;   // 8 bf16
typedef __attribute__((ext_vector_type(4))) float f32x4;

static __device__ __forceinline__ ushort f2bf(float x) {
  union { float f; unsigned u; } v; v.f = x;
  unsigned r = v.u + 0x7fff + ((v.u >> 16) & 1);
  return (ushort)(r >> 16);
}
static __device__ __forceinline__ float bf2f(ushort h) {
  union { float f; unsigned u; } v; v.u = ((unsigned)h) << 16;
  return v.f;
}

// ---------------- W prep: transpose + bf16 hi/lo split (unchanged, validated) ----
__global__ void prep_w(const float* __restrict__ W_in, const float* __restrict__ W_res,
                       ushort* __restrict__ Wth, ushort* __restrict__ Wtl) {
  __shared__ float tile[32][33];
  const int tk = blockIdx.x;             // 0..71
  const int tn = blockIdx.y;             // 0..63
  const int tx = threadIdx.x;            // 0..31
  const int ty = threadIdx.y;            // 0..7
  const int n = tn * 32 + tx;
  #pragma unroll
  for (int i = 0; i < 32; i += 8) {
    const int k = tk * 32 + ty + i;
    float v = 0.f;
    if (n < UNITS) {
      if (k < UNITS)            v = W_res[(size_t)k * UNITS + n];
      else if (k < UNITS+FDIM)  v = W_in[(size_t)(k - UNITS) * UNITS + n];
    }
    tile[ty + i][tx] = v;
  }
  __syncthreads();
  #pragma unroll
  for (int i = 0; i < 32; i += 8) {
    const int row = tn * 32 + ty + i;
    const int kk  = tk * 32 + tx;
    const float v = tile[tx][ty + i];
    const ushort hi = f2bf(v);
    const ushort lo = f2bf(v - bf2f(hi));
    Wth[(size_t)row * KPAD + kk] = hi;
    Wtl[(size_t)row * KPAD + kk] = lo;
  }
}

// ---------------- A-buffer + barrier init (runs every launch; ws is re-poisoned) --
__global__ void init_abuf(const float* __restrict__ inp,
                          ushort* a0h, ushort* a0l, ushort* a1h, ushort* a1l,
                          unsigned* bar) {
  const int i = blockIdx.x * 256 + threadIdx.x;
  if (i < 640) bar[i] = 0u;
  if (i >= AELEMS) return;
  ushort hi = 0, lo = 0;
  if (i < BATCH * KPAD) {
    const int b = i / KPAD, k = i % KPAD;
    if (k >= UNITS && k < UNITS + FDIM) {
      const float u = inp[(size_t)b * TSTEPS * FDIM + (k - UNITS)];   // t = 0
      hi = f2bf(u); lo = f2bf(u - bf2f(hi));
    }
  }
  a0h[i] = hi; a0l[i] = lo; a1h[i] = 0; a1l[i] = 0;
}

// ---------------- the scan ----------------
// 256 blocks x 256 thr, 1 block/CU (LDS-limited). Block (pb,cb): rows [pb*32,+32),
// cols [cb*16,+16). W col-slice (hi+lo) resident in LDS. 4 waves = 2 M-tiles x 2
// K-halves; fp32 reduction through LDS. bf16x3: ah*bh + ah*bl + al*bh.
__global__ void __launch_bounds__(256, 1)
esn_scan(const float* __restrict__ inp, const float* __restrict__ alpha,
         const ushort* __restrict__ Wth, const ushort* __restrict__ Wtl,
         ushort* __restrict__ a0h, ushort* __restrict__ a0l,
         ushort* __restrict__ a1h, ushort* __restrict__ a1l,
         float* __restrict__ out, unsigned* __restrict__ bar) {
  extern __shared__ ushort smem[];
  ushort* wH  = smem;                     // [16][WLSTR]
  ushort* wL  = smem + 16*WLSTR;
  float*  red = (float*)(smem + REDOFF);  // [2][64][4] fp32

  const int bid = blockIdx.x;
  const int pb  = bid & 1;
  const int cb  = bid >> 1;               // 0..127
  const int tid = threadIdx.x;
  const int w = tid >> 6, lane = tid & 63;
  const int l15 = lane & 15, lk = lane >> 4;
  const int mi = w & 1, ks = w >> 1;

  // one-time: stage W col-slice into LDS (padded stride)
  for (int c = 0; c < 16; ++c) {
    const uint4* sH = (const uint4*)(Wth + (size_t)(cb*16 + c) * KPAD);
    const uint4* sL = (const uint4*)(Wtl + (size_t)(cb*16 + c) * KPAD);
    uint4* dH = (uint4*)(wH + c*WLSTR);
    uint4* dL = (uint4*)(wL + c*WLSTR);
    for (int j = tid; j < KPAD/8; j += 256) { dH[j] = sH[j]; dL[j] = sL[j]; }
  }
  __syncthreads();

  const int kb = ks * 36;                 // this wave's K-half: ki in [kb, kb+36)
  const size_t abase = (size_t)(pb*32 + mi*16 + l15) * KPAD + (size_t)lk*8;
  const ushort* pB_h = wH + l15*WLSTR + lk*8;
  const ushort* pB_l = wL + l15*WLSTR + lk*8;

  const int ecol  = cb*16 + l15;          // epilogue col (D: col = lane&15)
  const int erow0 = pb*32 + mi*16 + lk*4; // epilogue row base (D: row = (lane>>4)*4+r)
  float av = 0.f;
  if (ks == 0 && ecol < UNITS) av = alpha[ecol];
  float hreg[4] = {0.f, 0.f, 0.f, 0.f};   // h carried in fp32 regs (waves ks==0)

  ushort *cAH = a0h, *cAL = a0l, *nAH = a1h, *nAL = a1l;
  unsigned* gcnt = bar + (bid & 15) * 32; // 16 groups of 16, monotone counters
  unsigned* root = bar + 520;
  unsigned* gen  = bar + 576;

  for (int t = 0; t < TSTEPS; ++t) {
    const ushort* pA_h = cAH + abase;
    const ushort* pA_l = cAL + abase;
    short8 Xah[6], Xal[6], Yah[6], Yal[6];
    f32x4 acc[2][3];
    #pragma unroll
    for (int a = 0; a < 2; ++a)
      #pragma unroll
      for (int b = 0; b < 3; ++b) acc[a][b] = (f32x4){0.f, 0.f, 0.f, 0.f};

#define PF(B, KS) { _Pragma("unroll") for (int j = 0; j < 6; ++j) { \
      B##ah[j] = *(const short8*)(pA_h + ((KS)+j)*32); \
      B##al[j] = *(const short8*)(pA_l + ((KS)+j)*32); } }
#define CM(B, KS) { _Pragma("unroll") for (int j = 0; j < 6; ++j) { \
      const short8 bh = *(const short8*)(pB_h + ((KS)+j)*32); \
      const short8 bl = *(const short8*)(pB_l + ((KS)+j)*32); \
      acc[j&1][0] = __builtin_amdgcn_mfma_f32_16x16x32_bf16(B##ah[j], bh, acc[j&1][0], 0,0,0); \
      acc[j&1][1] = __builtin_amdgcn_mfma_f32_16x16x32_bf16(B##ah[j], bl, acc[j&1][1], 0,0,0); \
      acc[j&1][2] = __builtin_amdgcn_mfma_f32_16x16x32_bf16(B##al[j], bh, acc[j&1][2], 0,0,0); } }

    // 6 groups of 6 ki, 2-buffer software pipeline (24 A-loads in flight at start)
    PF(X, kb);      PF(Y, kb+6);
    CM(X, kb);      PF(X, kb+12);
    CM(Y, kb+6);    PF(Y, kb+18);
    CM(X, kb+12);   PF(X, kb+24);
    CM(Y, kb+18);   PF(Y, kb+30);
    CM(X, kb+24);
    CM(Y, kb+30);
#undef PF
#undef CM

    f32x4 s = acc[0][0] + acc[0][1] + acc[0][2] + acc[1][0] + acc[1][1] + acc[1][2];
    if (ks == 1) *(f32x4*)(red + (mi*64 + lane)*4) = s;
    __syncthreads();
    if (ks == 0) {
      s += *(const f32x4*)(red + (mi*64 + lane)*4);
      if (ecol < UNITS) {
        #pragma unroll
        for (int r = 0; r < 4; ++r) {
          const float hn = (1.f - av) * hreg[r] + av * tanhf(s[r]);
          hreg[r] = hn;
          const ushort hi = f2bf(hn);
          nAH[(size_t)(erow0+r)*KPAD + ecol] = hi;
          nAL[(size_t)(erow0+r)*KPAD + ecol] = f2bf(hn - bf2f(hi));
          if (t == TSTEPS-1) out[(size_t)(erow0+r)*UNITS + ecol] = hn;
        }
      }
    } else if (cb < 32 && t + 1 < TSTEPS) {
      // u_{t+1} staging: 64 blocks (cb<32, both pb) stage one batch row each
      const int b  = pb*32 + cb;
      const int t2 = tid - 128;   // 0..127
      const float2 uv = *(const float2*)(inp + (size_t)b*TSTEPS*FDIM
                                             + (size_t)(t+1)*FDIM + t2*2);
      const ushort h0 = f2bf(uv.x), h1 = f2bf(uv.y);
      ushort2 hs = {h0, h1};
      ushort2 ls = {f2bf(uv.x - bf2f(h0)), f2bf(uv.y - bf2f(h1))};
      *(ushort2*)(nAH + (size_t)b*KPAD + UNITS + t2*2) = hs;
      *(ushort2*)(nAL + (size_t)b*KPAD + UNITS + t2*2) = ls;
    }
    __syncthreads();   // all A[nxt] stores drained (syncthreads waits vmcnt(0))

    if (t + 1 < TSTEPS) {
      if (tid == 0) {
        __builtin_amdgcn_fence(__ATOMIC_RELEASE, "agent");   // wb L2 once/step
        const unsigned target = (unsigned)(t + 1) * 16u;
        const unsigned old = __hip_atomic_fetch_add(gcnt, 1u, __ATOMIC_RELAXED,
                                                    __HIP_MEMORY_SCOPE_AGENT);
        if (old == target - 1u) {
          const unsigned o2 = __hip_atomic_fetch_add(root, 1u, __ATOMIC_RELAXED,
                                                     __HIP_MEMORY_SCOPE_AGENT);
          if (o2 == target - 1u)
            __hip_atomic_store(gen, (unsigned)(t + 1), __ATOMIC_RELAXED,
                               __HIP_MEMORY_SCOPE_AGENT);
        }
        while (__hip_atomic_load(gen, __ATOMIC_RELAXED, __HIP_MEMORY_SCOPE_AGENT)
               < (unsigned)(t + 1))
          __builtin_amdgcn_s_sleep(2);                        // relaxed poll: no inv storm
        __builtin_amdgcn_fence(__ATOMIC_ACQUIRE, "agent");    // inv L1/L2 once/step
      }
      __syncthreads();
    }
    ushort* tH = cAH; cAH = nAH; nAH = tH;
    ushort* tL = cAL; cAL = nAL; nAL = tL;
  }
}

// ---------------- launch ----------------
extern "C" void kernel_launch(void* const* d_in, const int* in_sizes, int n_in,
                              void* d_out, int out_size, void* d_ws, size_t ws_size,
                              hipStream_t stream) {
  const float* inp   = (const float*)d_in[0];   // (64,1024,256)
  const float* W_in  = (const float*)d_in[1];   // (256,2000)
  const float* W_res = (const float*)d_in[2];   // (2000,2000)
  const float* alpha = (const float*)d_in[3];   // (1,2000)
  float* out = (float*)d_out;                   // (64,2000)

  ushort* Wth = (ushort*)d_ws;
  ushort* Wtl = Wth + WELEMS;
  ushort* a0h = Wtl + WELEMS;
  ushort* a0l = a0h + AELEMS;
  ushort* a1h = a0l + AELEMS;
  ushort* a1l = a1h + AELEMS;
  unsigned* bar = (unsigned*)(a1l + AELEMS);    // 640 uints

  (void)hipFuncSetAttribute((const void*)esn_scan,
                            hipFuncAttributeMaxDynamicSharedMemorySize, SMEM_BYTES);

  hipLaunchKernelGGL(prep_w, dim3(KPAD/32, NPAD/32), dim3(32, 8), 0, stream,
                     W_in, W_res, Wth, Wtl);
  hipLaunchKernelGGL(init_abuf, dim3((AELEMS + 255) / 256), dim3(256), 0, stream,
                     inp, a0h, a0l, a1h, a1l, bar);
  hipLaunchKernelGGL(esn_scan, dim3(NBLK), dim3(256), SMEM_BYTES, stream,
                     inp, alpha, Wth, Wtl, a0h, a0l, a1h, a1l, out, bar);
}

// Round 3
// 6945.942 us; speedup vs baseline: 7.4911x; 3.3317x over previous
//
#include <hip/hip_runtime.h>
#include <hip/hip_bf16.h>

// ---------------- problem constants ----------------
#define UNITS    2000
#define FDIM     256
#define TSTEPS   1024
#define BATCH    64
#define KPAD     2304                 // 2000 h + 256 u + 48 pad = 32*72
#define NPAD     2048
#define WLSTR    2312                 // LDS W row stride (ushorts)
#define MT_STRIDE 73728               // ushorts per mtile = 72 ki * 1024
#define ABUF_USH 294912               // 4 mtiles * MT_STRIDE (per buffer)
#define WELEMS   ((size_t)NPAD * KPAD)
#define NBLK     250                  // 125 col-groups * 2 batch halves
#define SMEM_BYTES (2*16*WLSTR*2 + 14336)   // 147,968 + 14,336 = 162,304

typedef __attribute__((ext_vector_type(8))) short short8;   // 8 bf16
typedef __attribute__((ext_vector_type(4))) float f32x4;

static __device__ __forceinline__ ushort f2bf(float x) {
  union { float f; unsigned u; } v; v.f = x;
  unsigned r = v.u + 0x7fff + ((v.u >> 16) & 1);
  return (ushort)(r >> 16);
}
static __device__ __forceinline__ float bf2f(ushort h) {
  union { float f; unsigned u; } v; v.u = ((unsigned)h) << 16;
  return v.f;
}

// Coherent (L1/L2-bypassing, Infinity-Cache-backed) 16-B load / 2-B store.
template<int OFF>
static __device__ __forceinline__ short8 load_coh(unsigned voff, const ushort* base) {
  short8 r;
  asm volatile("global_load_dwordx4 %0, %1, %2 offset:%3 sc0 sc1"
               : "=v"(r) : "v"(voff), "s"(base), "n"(OFF));
  return r;
}
template<int OFF>
static __device__ __forceinline__ void store_coh(unsigned voff, ushort* base, ushort val) {
  const unsigned v32 = val;
  asm volatile("global_store_short %0, %1, %2 offset:%3 sc0 sc1"
               :: "v"(voff), "v"(v32), "s"(base), "n"(OFF) : "memory");
}

// ---------------- W prep: transpose + bf16 hi/lo split (validated r1/r2) ----
__global__ void prep_w(const float* __restrict__ W_in, const float* __restrict__ W_res,
                       ushort* __restrict__ Wth, ushort* __restrict__ Wtl) {
  __shared__ float tile[32][33];
  const int tk = blockIdx.x, tn = blockIdx.y;
  const int tx = threadIdx.x, ty = threadIdx.y;
  const int n = tn * 32 + tx;
  #pragma unroll
  for (int i = 0; i < 32; i += 8) {
    const int k = tk * 32 + ty + i;
    float v = 0.f;
    if (n < UNITS) {
      if (k < UNITS)            v = W_res[(size_t)k * UNITS + n];
      else if (k < UNITS+FDIM)  v = W_in[(size_t)(k - UNITS) * UNITS + n];
    }
    tile[ty + i][tx] = v;
  }
  __syncthreads();
  #pragma unroll
  for (int i = 0; i < 32; i += 8) {
    const int row = tn * 32 + ty + i;
    const int kk  = tk * 32 + tx;
    const float v = tile[tx][ty + i];
    const ushort hi = f2bf(v);
    const ushort lo = f2bf(v - bf2f(hi));
    Wth[(size_t)row * KPAD + kk] = hi;
    Wtl[(size_t)row * KPAD + kk] = lo;
  }
}

// ---------------- A-buffer (fragment layout) + barrier init ----------------
// ushort offset F(row,k,part) = (row>>4)*MT_STRIDE + (k>>5)*1024 + part*512
//                              + ((k>>3)&3)*128 + (row&15)*8 + (k&7)
__global__ void init_abuf(const float* __restrict__ inp,
                          ushort* __restrict__ a0, ushort* __restrict__ a1,
                          unsigned* __restrict__ bar) {
  const int i = blockIdx.x * 256 + threadIdx.x;
  if (i < 2048) bar[i] = 0u;
  if (i >= ABUF_USH) return;
  const int mtile = i / MT_STRIDE;
  const int r1 = i - mtile * MT_STRIDE;
  const int ki  = r1 >> 10;
  const int rem = r1 & 1023;
  const int part = rem >> 9;
  const int lk  = (rem >> 7) & 3;
  const int l15 = (rem >> 3) & 15;
  const int el  = rem & 7;
  const int row = mtile * 16 + l15;
  const int k   = ki * 32 + lk * 8 + el;
  ushort v = 0;
  if (k >= UNITS && k < UNITS + FDIM) {
    const float u = inp[(size_t)row * TSTEPS * FDIM + (k - UNITS)];   // t = 0
    const ushort hi = f2bf(u);
    v = part ? f2bf(u - bf2f(hi)) : hi;
  }
  a0[i] = v; a1[i] = 0;
}

// ---------------- the scan ----------------
// 250 blocks x 512 thr (8 waves), 1 block/CU. Block (pb,cb): rows [pb*32,+32),
// cols [cb*16,+16). Wave ks owns K-eighth (9 ki) x both 16-row M-tiles.
// bf16x3: ah*bh + ah*bl + al*bh, fp32 LDS reduction across the 8 K-waves.
__global__ void __launch_bounds__(512, 2)
esn_scan(const float* __restrict__ inp, const float* __restrict__ alpha,
         const ushort* __restrict__ Wth, const ushort* __restrict__ Wtl,
         ushort* __restrict__ a0, ushort* __restrict__ a1,
         float* __restrict__ out, unsigned* __restrict__ bar) {
  extern __shared__ ushort smem[];
  float* red = (float*)(smem + 2*16*WLSTR);   // [14][64] f32x4

  const int bid = blockIdx.x;
  const int pb = bid & 1, cb = bid >> 1;      // cb in [0,125)
  const int tid = threadIdx.x;
  const int ks = tid >> 6, lane = tid & 63;
  const int l15 = lane & 15, lk = lane >> 4;

  // ---- one-time: stage W col-slice (hi+lo) into LDS ----
  {
    const uint4* srcH = (const uint4*)(Wth + (size_t)cb * 16 * KPAD);
    const uint4* srcL = (const uint4*)(Wtl + (size_t)cb * 16 * KPAD);
    uint4* dstH = (uint4*)smem;
    uint4* dstL = (uint4*)(smem + 16*WLSTR);
    for (int idx = tid; idx < 16*(KPAD/8); idx += 512) {
      const int c = idx / (KPAD/8), j = idx - c*(KPAD/8);
      dstH[c*(WLSTR/8) + j] = srcH[idx];
      dstL[c*(WLSTR/8) + j] = srcL[idx];
    }
  }
  __syncthreads();

  const ushort* pBh = smem + l15*WLSTR + lk*8 + ks*9*32;
  const ushort* pBl = pBh + 16*WLSTR;

  // A-load byte voffsets (saddr = swapped buffer base)
  const unsigned voffA0 = 2u*((unsigned)((pb*2+0)*MT_STRIDE + ks*9*1024) + (unsigned)lane*8u);
  const unsigned voffA1 = voffA0 + 2u*MT_STRIDE;

  // epilogue mapping (wave 0): D lane l -> col l15, row lk*4+r (per mi tile)
  const int ecol = cb*16 + l15;
  const float av = (ks == 0) ? alpha[ecol] : 0.f;
  const unsigned voffE0 = 2u*((unsigned)((pb*2)*MT_STRIDE) + (unsigned)((ecol>>5)*1024
                        + ((ecol>>3)&3)*128 + (lk*4)*8 + (ecol&7)));
  const unsigned voffE1 = voffE0 + 2u*MT_STRIDE;
  float hreg[2][4] = {{0.f,0.f,0.f,0.f},{0.f,0.f,0.f,0.f}};

  // u-staging mapping (waves 4..7 of blocks cb<32): one batch row, 256 floats
  const int t2 = tid - 256;
  const int sb = pb*32 + cb;
  unsigned voffS = 0; const float* inpS = inp;
  if (tid >= 256 && cb < 32) {
    const int kS = UNITS + t2;
    voffS = 2u*((unsigned)((sb>>4)*MT_STRIDE) + (unsigned)((kS>>5)*1024
          + ((kS>>3)&3)*128 + (sb&15)*8 + (kS&7)));
    inpS = inp + (size_t)sb * TSTEPS * FDIM + t2;
  }

  const ushort* Acur = a0;
  ushort* Anxt = a1;

  const unsigned gi = (unsigned)(bid & 15);
  const unsigned leafsz = (gi < 10) ? 16u : 15u;
  unsigned* leafp = bar + gi*32;
  unsigned* rootp = bar + 520;
  unsigned* genp  = bar + 528;
  unsigned* ggenp = bar + 544 + gi*32;

  for (int t = 0; t < TSTEPS; ++t) {
    // ---- coherent A burst: 36 x 16 B per wave, fully coalesced ----
    short8 fh0[9], fl0[9], fh1[9], fl1[9];
    #pragma unroll
    for (int j = 0; j < 9; ++j) {
      const unsigned vo0 = voffA0 + (unsigned)j*2048u;
      const unsigned vo1 = voffA1 + (unsigned)j*2048u;
      fh0[j] = load_coh<0>(vo0, Acur);
      fl0[j] = load_coh<1024>(vo0, Acur);
      fh1[j] = load_coh<0>(vo1, Acur);
      fl1[j] = load_coh<1024>(vo1, Acur);
    }

    f32x4 acc[2][3];
    #pragma unroll
    for (int a = 0; a < 2; ++a)
      #pragma unroll
      for (int b = 0; b < 3; ++b) acc[a][b] = (f32x4){0.f,0.f,0.f,0.f};

#define COMPUTE(j) { \
      const short8 bh = *(const short8*)(pBh + (j)*32); \
      const short8 bl = *(const short8*)(pBl + (j)*32); \
      acc[0][0] = __builtin_amdgcn_mfma_f32_16x16x32_bf16(fh0[j], bh, acc[0][0], 0,0,0); \
      acc[0][1] = __builtin_amdgcn_mfma_f32_16x16x32_bf16(fh0[j], bl, acc[0][1], 0,0,0); \
      acc[0][2] = __builtin_amdgcn_mfma_f32_16x16x32_bf16(fl0[j], bh, acc[0][2], 0,0,0); \
      acc[1][0] = __builtin_amdgcn_mfma_f32_16x16x32_bf16(fh1[j], bh, acc[1][0], 0,0,0); \
      acc[1][1] = __builtin_amdgcn_mfma_f32_16x16x32_bf16(fh1[j], bl, acc[1][1], 0,0,0); \
      acc[1][2] = __builtin_amdgcn_mfma_f32_16x16x32_bf16(fl1[j], bh, acc[1][2], 0,0,0); }

    asm volatile("s_waitcnt vmcnt(16)" ::: "memory");   // first 5 ki (20 loads) done
    __builtin_amdgcn_sched_barrier(0);
    #pragma unroll
    for (int j = 0; j < 5; ++j) COMPUTE(j)
    asm volatile("s_waitcnt vmcnt(0)" ::: "memory");
    __builtin_amdgcn_sched_barrier(0);
    #pragma unroll
    for (int j = 5; j < 9; ++j) COMPUTE(j)
#undef COMPUTE

    f32x4 s0 = acc[0][0] + acc[0][1] + acc[0][2];
    f32x4 s1 = acc[1][0] + acc[1][1] + acc[1][2];
    if (ks != 0) {
      *(f32x4*)(red + (((ks-1)*2+0)*64 + lane)*4) = s0;
      *(f32x4*)(red + (((ks-1)*2+1)*64 + lane)*4) = s1;
    }
    __syncthreads();

    if (ks == 0) {
      #pragma unroll
      for (int q = 0; q < 7; ++q) {
        s0 += *(const f32x4*)(red + ((q*2+0)*64 + lane)*4);
        s1 += *(const f32x4*)(red + ((q*2+1)*64 + lane)*4);
      }
      #pragma unroll
      for (int r = 0; r < 4; ++r) {
        const float hn = (1.f-av)*hreg[0][r] + av*tanhf(s0[r]);
        hreg[0][r] = hn;
        const ushort hi = f2bf(hn);
        store_coh<0>(voffE0 + (unsigned)r*16u, Anxt, hi);
        store_coh<1024>(voffE0 + (unsigned)r*16u, Anxt, f2bf(hn - bf2f(hi)));
        if (t == TSTEPS-1) out[(size_t)(pb*32 + lk*4 + r)*UNITS + ecol] = hn;
      }
      #pragma unroll
      for (int r = 0; r < 4; ++r) {
        const float hn = (1.f-av)*hreg[1][r] + av*tanhf(s1[r]);
        hreg[1][r] = hn;
        const ushort hi = f2bf(hn);
        store_coh<0>(voffE1 + (unsigned)r*16u, Anxt, hi);
        store_coh<1024>(voffE1 + (unsigned)r*16u, Anxt, f2bf(hn - bf2f(hi)));
        if (t == TSTEPS-1) out[(size_t)(pb*32 + 16 + lk*4 + r)*UNITS + ecol] = hn;
      }
    } else if (tid >= 256 && cb < 32 && t+1 < TSTEPS) {
      const float u = inpS[(size_t)(t+1)*FDIM];
      const ushort hi = f2bf(u);
      store_coh<0>(voffS, Anxt, hi);
      store_coh<1024>(voffS, Anxt, f2bf(u - bf2f(hi)));
    }

    asm volatile("s_waitcnt vmcnt(0)" ::: "memory");  // h stores at coherence point
    __syncthreads();

    if (t + 1 < TSTEPS) {
      if (tid == 0) {
        const unsigned tgt = (unsigned)(t+1);
        const unsigned old = __hip_atomic_fetch_add(leafp, 1u, __ATOMIC_RELAXED,
                                                    __HIP_MEMORY_SCOPE_AGENT);
        if (old == tgt*leafsz - 1u) {
          const unsigned o2 = __hip_atomic_fetch_add(rootp, 1u, __ATOMIC_RELAXED,
                                                     __HIP_MEMORY_SCOPE_AGENT);
          if (o2 == tgt*16u - 1u)
            __hip_atomic_store(genp, tgt, __ATOMIC_RELAXED, __HIP_MEMORY_SCOPE_AGENT);
          while (__hip_atomic_load(genp, __ATOMIC_RELAXED, __HIP_MEMORY_SCOPE_AGENT) < tgt)
            __builtin_amdgcn_s_sleep(4);
          __hip_atomic_store(ggenp, tgt, __ATOMIC_RELAXED, __HIP_MEMORY_SCOPE_AGENT);
        } else {
          while (__hip_atomic_load(ggenp, __ATOMIC_RELAXED, __HIP_MEMORY_SCOPE_AGENT) < tgt)
            __builtin_amdgcn_s_sleep(4);
        }
      }
      __syncthreads();
    }
    const ushort* tmp = Acur; Acur = Anxt; Anxt = (ushort*)tmp;
  }
}

// ---------------- launch ----------------
extern "C" void kernel_launch(void* const* d_in, const int* in_sizes, int n_in,
                              void* d_out, int out_size, void* d_ws, size_t ws_size,
                              hipStream_t stream) {
  const float* inp   = (const float*)d_in[0];   // (64,1024,256)
  const float* W_in  = (const float*)d_in[1];   // (256,2000)
  const float* W_res = (const float*)d_in[2];   // (2000,2000)
  const float* alpha = (const float*)d_in[3];   // (1,2000)
  float* out = (float*)d_out;                   // (64,2000)

  ushort* Wth = (ushort*)d_ws;
  ushort* Wtl = Wth + WELEMS;
  ushort* a0  = Wtl + WELEMS;
  ushort* a1  = a0 + ABUF_USH;
  unsigned* bar = (unsigned*)(a1 + ABUF_USH);   // 2048 uints

  (void)hipFuncSetAttribute((const void*)esn_scan,
                            hipFuncAttributeMaxDynamicSharedMemorySize, SMEM_BYTES);

  hipLaunchKernelGGL(prep_w, dim3(KPAD/32, NPAD/32), dim3(32, 8), 0, stream,
                     W_in, W_res, Wth, Wtl);
  hipLaunchKernelGGL(init_abuf, dim3((ABUF_USH + 255) / 256), dim3(256), 0, stream,
                     inp, a0, a1, bar);
  hipLaunchKernelGGL(esn_scan, dim3(NBLK), dim3(512), SMEM_BYTES, stream,
                     inp, alpha, Wth, Wtl, a0, a1, out, bar);
}